// Round 23
// baseline (534.935 us; speedup 1.0000x reference)
//
#include <hip/hip_runtime.h>

typedef unsigned short u16;
typedef unsigned int   u32;

#define NB     512
#define NHEADS 8
#define HW     361
#define NPIX   184832      /* NB*HW */
#define NTOT   768
#define EPSBN  1e-5f
#define RS     0.17677669529663687f   /* sqrt(32)/32 */

typedef __bf16 bf16x8 __attribute__((ext_vector_type(8)));
typedef float  f32x4  __attribute__((ext_vector_type(4)));

__device__ __forceinline__ u16 f2bf(float f) {
  u32 u = __float_as_uint(f);
  u += 0x7fffu + ((u >> 16) & 1u);          // round-to-nearest-even
  return (u16)(u >> 16);
}
__device__ __forceinline__ float bf2f(u16 v) {
  return __uint_as_float(((u32)v) << 16);
}
__device__ __forceinline__ bf16x8 ldb8(const void* p) {
  return __builtin_bit_cast(bf16x8, *(const uint4*)p);
}
__device__ __forceinline__ float dot2(u32 a, u32 b) {
  return bf2f((u16)a) * bf2f((u16)b) + bf2f((u16)(a >> 16)) * bf2f((u16)(b >> 16));
}
__device__ __forceinline__ float dot8(uint4 a, uint4 b) {
  return dot2(a.x, b.x) + dot2(a.y, b.y) + dot2(a.z, b.z) + dot2(a.w, b.w);
}

// ---------------- kernel 0: W -> bf16 [768][256]; bias; zero sx
__global__ __launch_bounds__(256) void k_prep(
    const float* __restrict__ Wq, const float* __restrict__ bq,
    const float* __restrict__ Wk, const float* __restrict__ bk,
    const float* __restrict__ Wv, const float* __restrict__ bv,
    u16* __restrict__ Wall, float* __restrict__ ball,
    float* __restrict__ sx) {
  const int n = blockIdx.x, t = threadIdx.x;
  const float* src; const float* bs; int r;
  if (n < 256)      { src = Wq; bs = bq; r = n; }
  else if (n < 512) { src = Wk; bs = bk; r = n - 256; }
  else              { src = Wv; bs = bv; r = n - 512; }
  Wall[n * 256 + t] = f2bf(src[r * 256 + t]);
  if (t == 0) ball[n] = bs[r];
  if (n == 0) sx[t] = 0.f;
}

// ---------------- kernel 1: M partials + sx + fused xT write (x read ONCE)
// 256 blocks (2 images) x 512 thr; px-chunk 128 (64 KB LDS, 12 barriers total)
// swizzle: 16 granules/row, slot = (g&8) | ((g ^ (c&7)) & 7)
__global__ __launch_bounds__(512) void k_M(
    const float* __restrict__ x, u16* __restrict__ xT,
    float* __restrict__ Mpart, float* __restrict__ sx) {
  __shared__ u16 Als[256 * 128];                   // 64 KB
  const int tid = threadIdx.x, g = blockIdx.x;     // images 2g, 2g+1
  const int lane = tid & 63, w = tid >> 6;         // 8 waves
  const int l15 = lane & 15, kq = lane >> 4;
  const int sc  = tid >> 5;                        // staging c low (0..15)
  const int sq  = tid & 31;                        // staging px quad (0..31)
  const int wpx = tid & 63;                        // xT-write px in half-chunk
  const int wcs = tid >> 6;                        // xT-write c-slice (*32)
  char* Ab = (char*)Als;

  float sxp[16];
  f32x4 acc[2][16];
  #pragma unroll
  for (int i = 0; i < 16; ++i) sxp[i] = 0.f;
  #pragma unroll
  for (int f2 = 0; f2 < 16; ++f2) {
    acc[0][f2] = (f32x4){0.f, 0.f, 0.f, 0.f};
    acc[1][f2] = (f32x4){0.f, 0.f, 0.f, 0.f};
  }

  #pragma unroll 1
  for (int ch = 0; ch < 6; ++ch) {
    const int img = (ch >= 3) ? 1 : 0;
    const int px0 = (ch - img * 3) * 128;
    const int bb  = g * 2 + img;
    const int pb  = px0 + sq * 4;
    const int gq  = sq >> 1;                       // px granule 0..15
    // stage: 16 float4 loads/thread, [c][px] direct
    #pragma unroll
    for (int i = 0; i < 16; ++i) {
      const int c = sc + 16 * i;
      const float* xp = x + ((size_t)bb * 256 + c) * HW + pb;
      float v0, v1, v2, v3;
      if (pb + 3 < HW) {
        const float4 f4 = *(const float4*)xp;
        v0 = f4.x; v1 = f4.y; v2 = f4.z; v3 = f4.w;
      } else {
        v0 = (pb + 0 < HW) ? xp[0] : 0.f;
        v1 = (pb + 1 < HW) ? xp[1] : 0.f;
        v2 = (pb + 2 < HW) ? xp[2] : 0.f;
        v3 = (pb + 3 < HW) ? xp[3] : 0.f;
      }
      sxp[i] += v0 + v1 + v2 + v3;
      const u32 lo = (u32)f2bf(v0) | ((u32)f2bf(v1) << 16);
      const u32 hi = (u32)f2bf(v2) | ((u32)f2bf(v3) << 16);
      const int slot = (gq & 8) | ((gq ^ (c & 7)) & 7);
      *(uint2*)(Ab + c * 256 + slot * 16 + (sq & 1) * 8) = make_uint2(lo, hi);
    }
    __syncthreads();
    // MFMA: K=128 (4 steps); wave w owns c1 strip [32w, 32w+32), all 256 c2
    #pragma unroll
    for (int kk = 0; kk < 4; ++kk) {
      const int gl = kk * 4 + kq;                  // 0..15
      const int r0 = w * 32 + l15;
      const int r1 = r0 + 16;
      const bf16x8 a0 = ldb8(Ab + r0 * 256 + (((gl & 8) | ((gl ^ (r0 & 7)) & 7)) << 4));
      const bf16x8 a1 = ldb8(Ab + r1 * 256 + (((gl & 8) | ((gl ^ (r1 & 7)) & 7)) << 4));
      #pragma unroll
      for (int f2 = 0; f2 < 16; ++f2) {
        const int rb = f2 * 16 + l15;
        const bf16x8 b = ldb8(Ab + rb * 256 + (((gl & 8) | ((gl ^ (rb & 7)) & 7)) << 4));
        acc[0][f2] = __builtin_amdgcn_mfma_f32_16x16x32_bf16(a0, b, acc[0][f2], 0, 0, 0);
        acc[1][f2] = __builtin_amdgcn_mfma_f32_16x16x32_bf16(a1, b, acc[1][f2], 0, 0, 0);
      }
    }
    // fused xT write: 2 half-chunks of 64 px
    #pragma unroll
    for (int hh = 0; hh < 2; ++hh) {
      const int pxl = hh * 64 + wpx;
      const int pxg = px0 + pxl;
      if (pxg < HW) {
        const int gg2 = pxl >> 3;                  // granule 0..15
        __align__(16) u16 tmp[32];
        #pragma unroll
        for (int j = 0; j < 32; ++j) {
          const int c = wcs * 32 + j;
          const int slot = (gg2 & 8) | ((gg2 ^ (c & 7)) & 7);
          tmp[j] = Als[c * 128 + slot * 8 + (pxl & 7)];
        }
        uint4* dst = (uint4*)(xT + ((size_t)bb * HW + pxg) * 256 + wcs * 32);
        dst[0] = ((const uint4*)tmp)[0];
        dst[1] = ((const uint4*)tmp)[1];
        dst[2] = ((const uint4*)tmp)[2];
        dst[3] = ((const uint4*)tmp)[3];
      }
    }
    __syncthreads();
  }
  float* mp = Mpart + (size_t)g * 65536;
  #pragma unroll
  for (int f1 = 0; f1 < 2; ++f1)
    #pragma unroll
    for (int f2 = 0; f2 < 16; ++f2)
      #pragma unroll
      for (int j = 0; j < 4; ++j) {
        const int c1 = w * 32 + f1 * 16 + kq * 4 + j;
        const int c2 = f2 * 16 + l15;
        mp[c1 * 256 + c2] = acc[f1][f2][j];
      }
  // sx: reduce within 32-thread px-groups
  #pragma unroll
  for (int i = 0; i < 16; ++i) {
    float v = sxp[i];
    v += __shfl_down(v, 16); v += __shfl_down(v, 8);
    v += __shfl_down(v, 4);  v += __shfl_down(v, 2);
    v += __shfl_down(v, 1);
    if (sq == 0) atomicAdd(&sx[sc + 16 * i], v);
  }
}

// ---------------- kernel 1c: reduce 256 partials -> Mg (deterministic)
__global__ __launch_bounds__(256) void k_red(const float* __restrict__ Mpart,
                                             float* __restrict__ Mg) {
  const int i = blockIdx.x * 256 + threadIdx.x;
  float s = 0.f;
  #pragma unroll 8
  for (int sl = 0; sl < 256; ++sl) s += Mpart[(size_t)sl * 65536 + i];
  Mg[i] = s;
}

// ---------------- kernel 2: finalize BN via moments: s_all, t_all
__global__ __launch_bounds__(256) void k_stats2(
    const float* __restrict__ Mg, const float* __restrict__ sx,
    const float* __restrict__ Wq, const float* __restrict__ bq,
    const float* __restrict__ Wk, const float* __restrict__ bk,
    const float* __restrict__ Wv, const float* __restrict__ bv,
    const float* __restrict__ gQ, const float* __restrict__ betaQ,
    const float* __restrict__ gK, const float* __restrict__ betaK,
    const float* __restrict__ gV, const float* __restrict__ betaV,
    float* __restrict__ s_all, float* __restrict__ t_all) {
  __shared__ float ws[256];
  __shared__ float r1[4], r2[4];
  const int n = blockIdx.x, i = threadIdx.x;
  const int which = n >> 8, r = n & 255;
  const float* src = (which == 0) ? Wq : (which == 1) ? Wk : Wv;
  const float wi = src[r * 256 + i];
  ws[i] = wi;
  __syncthreads();
  float colsum = 0.f;
  #pragma unroll 4
  for (int j = 0; j < 256; ++j) colsum += Mg[j * 256 + i] * ws[j];
  float p1 = wi * sx[i];
  float p2 = wi * colsum;
  p1 += __shfl_down(p1, 32); p2 += __shfl_down(p2, 32);
  p1 += __shfl_down(p1, 16); p2 += __shfl_down(p2, 16);
  p1 += __shfl_down(p1, 8);  p2 += __shfl_down(p2, 8);
  p1 += __shfl_down(p1, 4);  p2 += __shfl_down(p2, 4);
  p1 += __shfl_down(p1, 2);  p2 += __shfl_down(p2, 2);
  p1 += __shfl_down(p1, 1);  p2 += __shfl_down(p2, 1);
  const int wv = i >> 6;
  if ((i & 63) == 0) { r1[wv] = p1; r2[wv] = p2; }
  __syncthreads();
  if (i == 0) {
    const float S1 = r1[0] + r1[1] + r1[2] + r1[3];
    const float S2 = r2[0] + r2[1] + r2[2] + r2[3];
    const float* bs = (which == 0) ? bq : (which == 1) ? bk : bv;
    const float* gs = (which == 0) ? gQ : (which == 1) ? gK : gV;
    const float* be = (which == 0) ? betaQ : (which == 1) ? betaK : betaV;
    const float b = bs[r];
    const float P = (float)NPIX;
    const float mean = (S1 + P * b) / P;
    const float Ey2  = (S2 + 2.f * b * S1 + P * b * b) / P;
    const float var  = Ey2 - mean * mean;
    const float s    = gs[r] * rsqrtf(var + EPSBN);
    s_all[n] = s;
    t_all[n] = be[r] - s * mean;
  }
}

// ---------------- kernel 3: fused QKV-GEMM + neighbor attention
// 16 images/block (grid 256 = 1 block/CU); softmax fused; 2 barriers/img
__global__ __launch_bounds__(768) void k_fused(
    const u16* __restrict__ xT, const u16* __restrict__ Wall,
    const float* __restrict__ ball,
    const float* __restrict__ s_all, const float* __restrict__ t_all,
    float* __restrict__ out) {
  __shared__ u16   Wl[96 * 256];                   // 48 KB, XOR-swizzled rows
  __shared__ __align__(16) u16 P[HW * 104];        // 75,088 B: [px][Q|K|V]
  __shared__ float stl[2 * 96];
  const int tid = threadIdx.x;
  const int wg  = blockIdx.x;                      // 0..255
  const int xcd = wg & 7, ii = wg >> 3;            // ii 0..31
  const int h   = ii & 7;
  const int g16 = xcd * 4 + (ii >> 3);             // image 16-group 0..31
  const int bb0 = g16 * 16;
  const char* Pb = (const char*)P;

  const int lane = tid & 63, wv = tid >> 6;
  const int l15 = lane & 15, kq = lane >> 4;

  const bool pact = tid < 2 * HW;
  const int  ppx  = pact ? ((tid < HW) ? tid : tid - HW) : 0;
  const int  poc0 = (tid < HW) ? 0 : 16;

  uint4 bfr[16];
  {
    const u16* xTb = xT + (size_t)bb0 * HW * 256;
    #pragma unroll
    for (int ks = 0; ks < 8; ++ks) {
      bfr[2 * ks]     = *(const uint4*)(xTb + (size_t)(wv * 32      + l15) * 256 + ks * 32 + kq * 8);
      bfr[2 * ks + 1] = *(const uint4*)(xTb + (size_t)(wv * 32 + 16 + l15) * 256 + ks * 32 + kq * 8);
    }
  }
  // residual prefetch from bf16 xT (channels h*32+poc0 .. +16, contiguous)
  float xres[16];
  if (pact) {
    const uint4* xr = (const uint4*)(xT + ((size_t)bb0 * HW + ppx) * 256 + h * 32 + poc0);
    const uint4 r0 = xr[0], r1 = xr[1];
    const u32 uu[8] = {r0.x, r0.y, r0.z, r0.w, r1.x, r1.y, r1.z, r1.w};
    #pragma unroll
    for (int p = 0; p < 8; ++p) {
      xres[2 * p]     = bf2f((u16)uu[p]);
      xres[2 * p + 1] = bf2f((u16)(uu[p] >> 16));
    }
  }
  if (tid < 96) {
    const int which = tid >> 5, c32 = tid & 31;
    const int n = which * 256 + h * 32 + c32;
    float s = s_all[n];
    float t = s * ball[n] + t_all[n];
    if (tid < 32) { s *= RS; t *= RS; }
    stl[tid] = s; stl[96 + tid] = t;
  }
  #pragma unroll
  for (int i = 0; i < 4; ++i) {
    const int gi = tid + i * 768;
    const int lr = gi >> 5, gg = gi & 31;
    const int which = lr >> 5, c32 = lr & 31;
    uint4 v = *(const uint4*)(Wall + (size_t)(which * 256 + h * 32 + c32) * 256 + gg * 8);
    const int slot = gg ^ (lr & 7);
    *(uint4*)((char*)Wl + lr * 512 + slot * 16) = v;
  }
  __syncthreads();

  #pragma unroll 1
  for (int im = 0; im < 16; ++im) {
    const int bb = bb0 + im;
    f32x4 acc[6][2];
    #pragma unroll
    for (int f = 0; f < 6; ++f) {
      acc[f][0] = (f32x4){0.f, 0.f, 0.f, 0.f};
      acc[f][1] = (f32x4){0.f, 0.f, 0.f, 0.f};
    }
    #pragma unroll
    for (int ks = 0; ks < 8; ++ks) {
      bf16x8 b0 = __builtin_bit_cast(bf16x8, bfr[2 * ks]);
      bf16x8 b1 = __builtin_bit_cast(bf16x8, bfr[2 * ks + 1]);
      const int slot = ((ks * 4 + kq) ^ (l15 & 7)) * 16;
      #pragma unroll
      for (int f = 0; f < 6; ++f) {
        const int lr = (f >> 1) * 32 + (f & 1) * 16 + l15;
        bf16x8 a = ldb8((const char*)Wl + lr * 512 + slot);
        acc[f][0] = __builtin_amdgcn_mfma_f32_16x16x32_bf16(a, b0, acc[f][0], 0, 0, 0);
        acc[f][1] = __builtin_amdgcn_mfma_f32_16x16x32_bf16(a, b1, acc[f][1], 0, 0, 0);
      }
    }
    if (im < 15) {                                 // prefetch next image B-frags
      const u16* xTb2 = xT + (size_t)(bb + 1) * HW * 256;
      #pragma unroll
      for (int ks = 0; ks < 8; ++ks) {
        bfr[2 * ks]     = *(const uint4*)(xTb2 + (size_t)(wv * 32      + l15) * 256 + ks * 32 + kq * 8);
        bfr[2 * ks + 1] = *(const uint4*)(xTb2 + (size_t)(wv * 32 + 16 + l15) * 256 + ks * 32 + kq * 8);
      }
    }
    #pragma unroll
    for (int f = 0; f < 6; ++f) {
      const int ch0 = f * 16 + kq * 4;
      const float s0 = stl[ch0],     t0 = stl[96 + ch0];
      const float s1 = stl[ch0 + 1], t1 = stl[96 + ch0 + 1];
      const float s2 = stl[ch0 + 2], t2 = stl[96 + ch0 + 2];
      const float s3 = stl[ch0 + 3], t3 = stl[96 + ch0 + 3];
      #pragma unroll
      for (int p2 = 0; p2 < 2; ++p2) {
        const int px = wv * 32 + p2 * 16 + l15;
        if (px < HW) {
          const u32 lo = (u32)f2bf(s0 * acc[f][p2][0] + t0)
                       | ((u32)f2bf(s1 * acc[f][p2][1] + t1) << 16);
          const u32 hi = (u32)f2bf(s2 * acc[f][p2][2] + t2)
                       | ((u32)f2bf(s3 * acc[f][p2][3] + t3) << 16);
          *(uint2*)((char*)P + px * 208 + f * 32 + kq * 8) = make_uint2(lo, hi);
        }
      }
    }
    __syncthreads();

    // fused softmax + weighted-V + ReLU + residual (each thread owns (px, oc-half))
    if (pact) {
      const int px = ppx;
      const size_t pgb = ((size_t)bb * 256 + h * 32 + poc0) * HW + px;
      const int yy = px / 19, xx = px - yy * 19;
      const bool i0 = yy > 0, i1 = yy < 18, i2 = xx > 0, i3 = xx < 18;
      const int pn0 = i0 ? px - 19 : px, pn1 = i1 ? px + 19 : px;
      const int pn2 = i2 ? px - 1  : px, pn3 = i3 ? px + 1  : px;
      const uint4* Qp = (const uint4*)(Pb + px * 208);
      const uint4 q0 = Qp[0], q1 = Qp[1], q2 = Qp[2], q3 = Qp[3];
      const uint4* K0 = (const uint4*)(Pb + pn0 * 208 + 64);
      const uint4* K1 = (const uint4*)(Pb + pn1 * 208 + 64);
      const uint4* K2 = (const uint4*)(Pb + pn2 * 208 + 64);
      const uint4* K3 = (const uint4*)(Pb + pn3 * 208 + 64);
      float l0 = dot8(q0, K0[0]) + dot8(q1, K0[1]) + dot8(q2, K0[2]) + dot8(q3, K0[3]);
      float l1 = dot8(q0, K1[0]) + dot8(q1, K1[1]) + dot8(q2, K1[2]) + dot8(q3, K1[3]);
      float l2 = dot8(q0, K2[0]) + dot8(q1, K2[1]) + dot8(q2, K2[2]) + dot8(q3, K2[3]);
      float l3 = dot8(q0, K3[0]) + dot8(q1, K3[1]) + dot8(q2, K3[2]) + dot8(q3, K3[3]);
      l0 = i0 ? l0 : 0.f; l1 = i1 ? l1 : 0.f;
      l2 = i2 ? l2 : 0.f; l3 = i3 ? l3 : 0.f;
      const float mx = fmaxf(fmaxf(l0, l1), fmaxf(l2, l3));
      const float e0 = __expf(l0 - mx), e1 = __expf(l1 - mx);
      const float e2 = __expf(l2 - mx), e3 = __expf(l3 - mx);
      const float inv = 1.f / (e0 + e1 + e2 + e3);
      const float a0 = i0 ? e0 * inv : 0.f;
      const float a1 = i1 ? e1 * inv : 0.f;
      const float a2 = i2 ? e2 * inv : 0.f;
      const float a3 = i3 ? e3 * inv : 0.f;
      const int vb = 128 + poc0 * 2;
      const uint4* V0 = (const uint4*)(Pb + pn0 * 208 + vb);
      const uint4* V1 = (const uint4*)(Pb + pn1 * 208 + vb);
      const uint4* V2 = (const uint4*)(Pb + pn2 * 208 + vb);
      const uint4* V3 = (const uint4*)(Pb + pn3 * 208 + vb);
      #pragma unroll
      for (int half = 0; half < 2; ++half) {
        const uint4 w0 = V0[half], w1 = V1[half], w2 = V2[half], w3 = V3[half];
        const u32 u0[4] = {w0.x, w0.y, w0.z, w0.w};
        const u32 u1[4] = {w1.x, w1.y, w1.z, w1.w};
        const u32 u2[4] = {w2.x, w2.y, w2.z, w2.w};
        const u32 u3[4] = {w3.x, w3.y, w3.z, w3.w};
        #pragma unroll
        for (int p = 0; p < 4; ++p) {
          const int o = half * 8 + p * 2;
          float vlo = a0 * bf2f((u16)u0[p]) + a1 * bf2f((u16)u1[p])
                    + a2 * bf2f((u16)u2[p]) + a3 * bf2f((u16)u3[p]);
          float vhi = a0 * bf2f((u16)(u0[p] >> 16)) + a1 * bf2f((u16)(u1[p] >> 16))
                    + a2 * bf2f((u16)(u2[p] >> 16)) + a3 * bf2f((u16)(u3[p] >> 16));
          vlo = fmaxf(vlo, 0.f);
          vhi = fmaxf(vhi, 0.f);
          out[pgb + (size_t)o * HW]       = vlo + xres[o];
          out[pgb + (size_t)(o + 1) * HW] = vhi + xres[o + 1];
        }
      }
    }
    if (im < 15 && pact) {                         // prefetch next image residual
      const uint4* xr2 = (const uint4*)(xT + ((size_t)(bb + 1) * HW + ppx) * 256 + h * 32 + poc0);
      const uint4 r0 = xr2[0], r1 = xr2[1];
      const u32 uu[8] = {r0.x, r0.y, r0.z, r0.w, r1.x, r1.y, r1.z, r1.w};
      #pragma unroll
      for (int p = 0; p < 8; ++p) {
        xres[2 * p]     = bf2f((u16)uu[p]);
        xres[2 * p + 1] = bf2f((u16)(uu[p] >> 16));
      }
    }
    __syncthreads();
  }
}

// ---------------- workspace layout
constexpr size_t OFF_XT    = 0;
constexpr size_t SZ_XT     = (size_t)NPIX * 512 + 16384;
constexpr size_t OFF_WALL  = OFF_XT + SZ_XT;
constexpr size_t SZ_WALL   = (size_t)NTOT * 512;
constexpr size_t OFF_BALL  = OFF_WALL + SZ_WALL;
constexpr size_t OFF_M     = OFF_BALL + NTOT * 4;
constexpr size_t SZ_M      = 256 * 256 * 4;
constexpr size_t OFF_SX    = OFF_M + SZ_M;
constexpr size_t OFF_SALL  = OFF_SX + 256 * 4;
constexpr size_t OFF_TALL  = OFF_SALL + NTOT * 4;
constexpr size_t OFF_MPART = OFF_TALL + NTOT * 4;
constexpr size_t SZ_MPART  = (size_t)256 * 65536 * 4;   // 67 MB
constexpr size_t WS_NEEDED = OFF_MPART + SZ_MPART;

extern "C" void kernel_launch(void* const* d_in, const int* in_sizes, int n_in,
                              void* d_out, int out_size, void* d_ws, size_t ws_size,
                              hipStream_t stream) {
  (void)in_sizes; (void)n_in; (void)out_size;
  if (ws_size < WS_NEEDED) return;

  const float* x     = (const float*)d_in[0];
  const float* Wq    = (const float*)d_in[1];
  const float* bq    = (const float*)d_in[2];
  const float* Wk    = (const float*)d_in[3];
  const float* bk    = (const float*)d_in[4];
  const float* Wv    = (const float*)d_in[5];
  const float* bv    = (const float*)d_in[6];
  const float* gQ    = (const float*)d_in[7];
  const float* betaQ = (const float*)d_in[8];
  const float* gK    = (const float*)d_in[9];
  const float* betaK = (const float*)d_in[10];
  const float* gV    = (const float*)d_in[11];
  const float* betaV = (const float*)d_in[12];
  float* out = (float*)d_out;

  char* wsp = (char*)d_ws;
  u16*   xT    = (u16*)(wsp + OFF_XT);
  u16*   Wall  = (u16*)(wsp + OFF_WALL);
  float* ball  = (float*)(wsp + OFF_BALL);
  float* Mg    = (float*)(wsp + OFF_M);
  float* sx    = (float*)(wsp + OFF_SX);
  float* s_all = (float*)(wsp + OFF_SALL);
  float* t_all = (float*)(wsp + OFF_TALL);
  float* Mpart = (float*)(wsp + OFF_MPART);

  k_prep<<<NTOT, 256, 0, stream>>>(Wq, bq, Wk, bk, Wv, bv, Wall, ball, sx);
  k_M<<<256, 512, 0, stream>>>(x, xT, Mpart, sx);
  k_red<<<256, 256, 0, stream>>>(Mpart, Mg);
  k_stats2<<<NTOT, 256, 0, stream>>>(Mg, sx, Wq, bq, Wk, bk, Wv, bv,
                                     gQ, betaQ, gK, betaK, gV, betaV, s_all, t_all);
  k_fused<<<256, 768, 0, stream>>>(xT, Wall, ball, s_all, t_all, out);
}

// Round 24
// 355.425 us; speedup vs baseline: 1.5051x; 1.5051x over previous
//
#include <hip/hip_runtime.h>

typedef unsigned short u16;
typedef unsigned int   u32;

#define NB     512
#define NHEADS 8
#define HW     361
#define NPIX   184832      /* NB*HW */
#define NTOT   768
#define EPSBN  1e-5f
#define RS     0.17677669529663687f   /* sqrt(32)/32 */

typedef __bf16 bf16x8 __attribute__((ext_vector_type(8)));
typedef float  f32x4  __attribute__((ext_vector_type(4)));

__device__ __forceinline__ u16 f2bf(float f) {
  u32 u = __float_as_uint(f);
  u += 0x7fffu + ((u >> 16) & 1u);          // round-to-nearest-even
  return (u16)(u >> 16);
}
__device__ __forceinline__ float bf2f(u16 v) {
  return __uint_as_float(((u32)v) << 16);
}
__device__ __forceinline__ bf16x8 ldb8(const void* p) {
  return __builtin_bit_cast(bf16x8, *(const uint4*)p);
}
__device__ __forceinline__ float dot2(u32 a, u32 b) {
  return bf2f((u16)a) * bf2f((u16)b) + bf2f((u16)(a >> 16)) * bf2f((u16)(b >> 16));
}
__device__ __forceinline__ float dot8(uint4 a, uint4 b) {
  return dot2(a.x, b.x) + dot2(a.y, b.y) + dot2(a.z, b.z) + dot2(a.w, b.w);
}

// ---------------- kernel 0: W -> bf16 [768][256]; bias; zero sx
__global__ __launch_bounds__(256) void k_prep(
    const float* __restrict__ Wq, const float* __restrict__ bq,
    const float* __restrict__ Wk, const float* __restrict__ bk,
    const float* __restrict__ Wv, const float* __restrict__ bv,
    u16* __restrict__ Wall, float* __restrict__ ball,
    float* __restrict__ sx) {
  const int n = blockIdx.x, t = threadIdx.x;
  const float* src; const float* bs; int r;
  if (n < 256)      { src = Wq; bs = bq; r = n; }
  else if (n < 512) { src = Wk; bs = bk; r = n - 256; }
  else              { src = Wv; bs = bv; r = n - 512; }
  Wall[n * 256 + t] = f2bf(src[r * 256 + t]);
  if (t == 0) ball[n] = bs[r];
  if (n == 0) sx[t] = 0.f;
}

// ---------------- kernel 1: M partials + sx + fused xT write (x read ONCE)
// R16 version (known-good): 256 blocks (2 images) x 512 thr; acc[2][16]
__global__ __launch_bounds__(512) void k_M(
    const float* __restrict__ x, u16* __restrict__ xT,
    float* __restrict__ Mpart, float* __restrict__ sx) {
  __shared__ u16 Als[256 * 64];                    // 32 KB
  const int tid = threadIdx.x, g = blockIdx.x;     // images 2g, 2g+1
  const int lane = tid & 63, w = tid >> 6;         // 8 waves
  const int l15 = lane & 15, kq = lane >> 4;
  const int sc  = tid >> 4;                        // staging c low (0..31)
  const int sq  = tid & 15;                        // staging px quad
  const int wpx = tid & 63;                        // xT-write px in chunk
  const int wcs = tid >> 6;                        // xT-write c-slice (*32)
  char* Ab = (char*)Als;

  float sxp[8];
  f32x4 acc[2][16];
  #pragma unroll
  for (int i = 0; i < 8; ++i) sxp[i] = 0.f;
  #pragma unroll
  for (int f2 = 0; f2 < 16; ++f2) {
    acc[0][f2] = (f32x4){0.f, 0.f, 0.f, 0.f};
    acc[1][f2] = (f32x4){0.f, 0.f, 0.f, 0.f};
  }

  #pragma unroll 1
  for (int ch = 0; ch < 12; ++ch) {
    const int img = (ch >= 6) ? 1 : 0;
    const int px0 = (ch - img * 6) * 64;
    const int bb  = g * 2 + img;
    const int pb  = px0 + sq * 4;
    #pragma unroll
    for (int i = 0; i < 8; ++i) {
      const int c = sc + 32 * i;
      const float* xp = x + ((size_t)bb * 256 + c) * HW + pb;
      float v0, v1, v2, v3;
      if (pb + 3 < HW) {
        const float4 f4 = *(const float4*)xp;
        v0 = f4.x; v1 = f4.y; v2 = f4.z; v3 = f4.w;
      } else {
        v0 = (pb + 0 < HW) ? xp[0] : 0.f;
        v1 = (pb + 1 < HW) ? xp[1] : 0.f;
        v2 = (pb + 2 < HW) ? xp[2] : 0.f;
        v3 = (pb + 3 < HW) ? xp[3] : 0.f;
      }
      sxp[i] += v0 + v1 + v2 + v3;
      const u32 lo = (u32)f2bf(v0) | ((u32)f2bf(v1) << 16);
      const u32 hi = (u32)f2bf(v2) | ((u32)f2bf(v3) << 16);
      const int slot = (sq >> 1) ^ (c & 7);        // XOR swizzle
      *(uint2*)(Ab + c * 128 + slot * 16 + (sq & 1) * 8) = make_uint2(lo, hi);
    }
    __syncthreads();
    #pragma unroll
    for (int kk = 0; kk < 2; ++kk) {
      const int gl = kk * 4 + kq;
      const int so = ((gl ^ (l15 & 7)) << 4);
      const int r0 = w * 32 + l15;
      const bf16x8 a0 = ldb8(Ab + r0 * 128 + so);
      const bf16x8 a1 = ldb8(Ab + (r0 + 16) * 128 + so);
      #pragma unroll
      for (int f2 = 0; f2 < 16; ++f2) {
        const bf16x8 b = ldb8(Ab + (f2 * 16 + l15) * 128 + so);
        acc[0][f2] = __builtin_amdgcn_mfma_f32_16x16x32_bf16(a0, b, acc[0][f2], 0, 0, 0);
        acc[1][f2] = __builtin_amdgcn_mfma_f32_16x16x32_bf16(a1, b, acc[1][f2], 0, 0, 0);
      }
    }
    const int pxg = px0 + wpx;
    if (pxg < HW) {
      __align__(16) u16 tmp[32];
      #pragma unroll
      for (int j = 0; j < 32; ++j) {
        const int c = wcs * 32 + j;
        tmp[j] = Als[c * 64 + (((wpx >> 3) ^ (c & 7)) << 3) + (wpx & 7)];
      }
      uint4* dst = (uint4*)(xT + ((size_t)bb * HW + pxg) * 256 + wcs * 32);
      dst[0] = ((const uint4*)tmp)[0];
      dst[1] = ((const uint4*)tmp)[1];
      dst[2] = ((const uint4*)tmp)[2];
      dst[3] = ((const uint4*)tmp)[3];
    }
    __syncthreads();
  }
  float* mp = Mpart + (size_t)g * 65536;
  #pragma unroll
  for (int f1 = 0; f1 < 2; ++f1)
    #pragma unroll
    for (int f2 = 0; f2 < 16; ++f2)
      #pragma unroll
      for (int j = 0; j < 4; ++j) {
        const int c1 = w * 32 + f1 * 16 + kq * 4 + j;
        const int c2 = f2 * 16 + l15;
        mp[c1 * 256 + c2] = acc[f1][f2][j];
      }
  #pragma unroll
  for (int i = 0; i < 8; ++i) {
    float v = sxp[i];
    v += __shfl_down(v, 8); v += __shfl_down(v, 4);
    v += __shfl_down(v, 2); v += __shfl_down(v, 1);
    if (sq == 0) atomicAdd(&sx[sc + 32 * i], v);
  }
}

// ---------------- kernel 1c: reduce 256 partials -> Mg (deterministic)
__global__ __launch_bounds__(256) void k_red(const float* __restrict__ Mpart,
                                             float* __restrict__ Mg) {
  const int i = blockIdx.x * 256 + threadIdx.x;
  float s = 0.f;
  #pragma unroll 8
  for (int sl = 0; sl < 256; ++sl) s += Mpart[(size_t)sl * 65536 + i];
  Mg[i] = s;
}

// ---------------- kernel 2: finalize BN via moments: s_all, t_all
__global__ __launch_bounds__(256) void k_stats2(
    const float* __restrict__ Mg, const float* __restrict__ sx,
    const float* __restrict__ Wq, const float* __restrict__ bq,
    const float* __restrict__ Wk, const float* __restrict__ bk,
    const float* __restrict__ Wv, const float* __restrict__ bv,
    const float* __restrict__ gQ, const float* __restrict__ betaQ,
    const float* __restrict__ gK, const float* __restrict__ betaK,
    const float* __restrict__ gV, const float* __restrict__ betaV,
    float* __restrict__ s_all, float* __restrict__ t_all) {
  __shared__ float ws[256];
  __shared__ float r1[4], r2[4];
  const int n = blockIdx.x, i = threadIdx.x;
  const int which = n >> 8, r = n & 255;
  const float* src = (which == 0) ? Wq : (which == 1) ? Wk : Wv;
  const float wi = src[r * 256 + i];
  ws[i] = wi;
  __syncthreads();
  float colsum = 0.f;
  #pragma unroll 4
  for (int j = 0; j < 256; ++j) colsum += Mg[j * 256 + i] * ws[j];
  float p1 = wi * sx[i];
  float p2 = wi * colsum;
  p1 += __shfl_down(p1, 32); p2 += __shfl_down(p2, 32);
  p1 += __shfl_down(p1, 16); p2 += __shfl_down(p2, 16);
  p1 += __shfl_down(p1, 8);  p2 += __shfl_down(p2, 8);
  p1 += __shfl_down(p1, 4);  p2 += __shfl_down(p2, 4);
  p1 += __shfl_down(p1, 2);  p2 += __shfl_down(p2, 2);
  p1 += __shfl_down(p1, 1);  p2 += __shfl_down(p2, 1);
  const int wv = i >> 6;
  if ((i & 63) == 0) { r1[wv] = p1; r2[wv] = p2; }
  __syncthreads();
  if (i == 0) {
    const float S1 = r1[0] + r1[1] + r1[2] + r1[3];
    const float S2 = r2[0] + r2[1] + r2[2] + r2[3];
    const float* bs = (which == 0) ? bq : (which == 1) ? bk : bv;
    const float* gs = (which == 0) ? gQ : (which == 1) ? gK : gV;
    const float* be = (which == 0) ? betaQ : (which == 1) ? betaK : betaV;
    const float b = bs[r];
    const float P = (float)NPIX;
    const float mean = (S1 + P * b) / P;
    const float Ey2  = (S2 + 2.f * b * S1 + P * b * b) / P;
    const float var  = Ey2 - mean * mean;
    const float s    = gs[r] * rsqrtf(var + EPSBN);
    s_all[n] = s;
    t_all[n] = be[r] - s * mean;
  }
}

// ---------------- kernel 3: fused QKV-GEMM + neighbor attention
// 8 images/block (grid 512); softmax fused into output phase; 2 barriers/img
__global__ __launch_bounds__(768) void k_fused(
    const u16* __restrict__ xT, const u16* __restrict__ Wall,
    const float* __restrict__ ball,
    const float* __restrict__ s_all, const float* __restrict__ t_all,
    float* __restrict__ out) {
  __shared__ u16   Wl[96 * 256];                   // 48 KB, XOR-swizzled rows
  __shared__ __align__(16) u16 P[HW * 104];        // 75,088 B: [px][Q|K|V]
  __shared__ float stl[2 * 96];
  const int tid = threadIdx.x;
  const int wg  = blockIdx.x;                      // 0..511
  const int xcd = wg & 7, ii = wg >> 3;            // ii 0..63
  const int h   = ii & 7;
  const int oc8 = xcd * 8 + (ii >> 3);             // image octet 0..63
  const int bb0 = oc8 * 8;
  const char* Pb = (const char*)P;

  const int lane = tid & 63, wv = tid >> 6;
  const int l15 = lane & 15, kq = lane >> 4;

  const bool pact = tid < 2 * HW;
  const int  ppx  = pact ? ((tid < HW) ? tid : tid - HW) : 0;
  const int  poc0 = (tid < HW) ? 0 : 16;

  uint4 bfr[16];
  {
    const u16* xTb = xT + (size_t)bb0 * HW * 256;
    #pragma unroll
    for (int ks = 0; ks < 8; ++ks) {
      bfr[2 * ks]     = *(const uint4*)(xTb + (size_t)(wv * 32      + l15) * 256 + ks * 32 + kq * 8);
      bfr[2 * ks + 1] = *(const uint4*)(xTb + (size_t)(wv * 32 + 16 + l15) * 256 + ks * 32 + kq * 8);
    }
  }
  // residual prefetch from bf16 xT (channels h*32+poc0 .. +16, contiguous)
  float xres[16];
  if (pact) {
    const uint4* xr = (const uint4*)(xT + ((size_t)bb0 * HW + ppx) * 256 + h * 32 + poc0);
    const uint4 r0 = xr[0], r1 = xr[1];
    const u32 uu[8] = {r0.x, r0.y, r0.z, r0.w, r1.x, r1.y, r1.z, r1.w};
    #pragma unroll
    for (int p = 0; p < 8; ++p) {
      xres[2 * p]     = bf2f((u16)uu[p]);
      xres[2 * p + 1] = bf2f((u16)(uu[p] >> 16));
    }
  }
  if (tid < 96) {
    const int which = tid >> 5, c32 = tid & 31;
    const int n = which * 256 + h * 32 + c32;
    float s = s_all[n];
    float t = s * ball[n] + t_all[n];
    if (tid < 32) { s *= RS; t *= RS; }
    stl[tid] = s; stl[96 + tid] = t;
  }
  #pragma unroll
  for (int i = 0; i < 4; ++i) {
    const int gi = tid + i * 768;
    const int lr = gi >> 5, gg = gi & 31;
    const int which = lr >> 5, c32 = lr & 31;
    uint4 v = *(const uint4*)(Wall + (size_t)(which * 256 + h * 32 + c32) * 256 + gg * 8);
    const int slot = gg ^ (lr & 7);
    *(uint4*)((char*)Wl + lr * 512 + slot * 16) = v;
  }
  __syncthreads();

  #pragma unroll 1
  for (int im = 0; im < 8; ++im) {
    const int bb = bb0 + im;
    f32x4 acc[6][2];
    #pragma unroll
    for (int f = 0; f < 6; ++f) {
      acc[f][0] = (f32x4){0.f, 0.f, 0.f, 0.f};
      acc[f][1] = (f32x4){0.f, 0.f, 0.f, 0.f};
    }
    #pragma unroll
    for (int ks = 0; ks < 8; ++ks) {
      bf16x8 b0 = __builtin_bit_cast(bf16x8, bfr[2 * ks]);
      bf16x8 b1 = __builtin_bit_cast(bf16x8, bfr[2 * ks + 1]);
      const int slot = ((ks * 4 + kq) ^ (l15 & 7)) * 16;
      #pragma unroll
      for (int f = 0; f < 6; ++f) {
        const int lr = (f >> 1) * 32 + (f & 1) * 16 + l15;
        bf16x8 a = ldb8((const char*)Wl + lr * 512 + slot);
        acc[f][0] = __builtin_amdgcn_mfma_f32_16x16x32_bf16(a, b0, acc[f][0], 0, 0, 0);
        acc[f][1] = __builtin_amdgcn_mfma_f32_16x16x32_bf16(a, b1, acc[f][1], 0, 0, 0);
      }
    }
    if (im < 7) {                                  // prefetch next image B-frags
      const u16* xTb2 = xT + (size_t)(bb + 1) * HW * 256;
      #pragma unroll
      for (int ks = 0; ks < 8; ++ks) {
        bfr[2 * ks]     = *(const uint4*)(xTb2 + (size_t)(wv * 32      + l15) * 256 + ks * 32 + kq * 8);
        bfr[2 * ks + 1] = *(const uint4*)(xTb2 + (size_t)(wv * 32 + 16 + l15) * 256 + ks * 32 + kq * 8);
      }
    }
    #pragma unroll
    for (int f = 0; f < 6; ++f) {
      const int ch0 = f * 16 + kq * 4;
      const float s0 = stl[ch0],     t0 = stl[96 + ch0];
      const float s1 = stl[ch0 + 1], t1 = stl[96 + ch0 + 1];
      const float s2 = stl[ch0 + 2], t2 = stl[96 + ch0 + 2];
      const float s3 = stl[ch0 + 3], t3 = stl[96 + ch0 + 3];
      #pragma unroll
      for (int p2 = 0; p2 < 2; ++p2) {
        const int px = wv * 32 + p2 * 16 + l15;
        if (px < HW) {
          const u32 lo = (u32)f2bf(s0 * acc[f][p2][0] + t0)
                       | ((u32)f2bf(s1 * acc[f][p2][1] + t1) << 16);
          const u32 hi = (u32)f2bf(s2 * acc[f][p2][2] + t2)
                       | ((u32)f2bf(s3 * acc[f][p2][3] + t3) << 16);
          *(uint2*)((char*)P + px * 208 + f * 32 + kq * 8) = make_uint2(lo, hi);
        }
      }
    }
    __syncthreads();

    // fused softmax + weighted-V + ReLU + residual (each thread owns (px, oc-half))
    if (pact) {
      const int px = ppx;
      const size_t pgb = ((size_t)bb * 256 + h * 32 + poc0) * HW + px;
      const int yy = px / 19, xx = px - yy * 19;
      const bool i0 = yy > 0, i1 = yy < 18, i2 = xx > 0, i3 = xx < 18;
      const int pn0 = i0 ? px - 19 : px, pn1 = i1 ? px + 19 : px;
      const int pn2 = i2 ? px - 1  : px, pn3 = i3 ? px + 1  : px;
      const uint4* Qp = (const uint4*)(Pb + px * 208);
      const uint4 q0 = Qp[0], q1 = Qp[1], q2 = Qp[2], q3 = Qp[3];
      const uint4* K0 = (const uint4*)(Pb + pn0 * 208 + 64);
      const uint4* K1 = (const uint4*)(Pb + pn1 * 208 + 64);
      const uint4* K2 = (const uint4*)(Pb + pn2 * 208 + 64);
      const uint4* K3 = (const uint4*)(Pb + pn3 * 208 + 64);
      float l0 = dot8(q0, K0[0]) + dot8(q1, K0[1]) + dot8(q2, K0[2]) + dot8(q3, K0[3]);
      float l1 = dot8(q0, K1[0]) + dot8(q1, K1[1]) + dot8(q2, K1[2]) + dot8(q3, K1[3]);
      float l2 = dot8(q0, K2[0]) + dot8(q1, K2[1]) + dot8(q2, K2[2]) + dot8(q3, K2[3]);
      float l3 = dot8(q0, K3[0]) + dot8(q1, K3[1]) + dot8(q2, K3[2]) + dot8(q3, K3[3]);
      l0 = i0 ? l0 : 0.f; l1 = i1 ? l1 : 0.f;
      l2 = i2 ? l2 : 0.f; l3 = i3 ? l3 : 0.f;
      const float mx = fmaxf(fmaxf(l0, l1), fmaxf(l2, l3));
      const float e0 = __expf(l0 - mx), e1 = __expf(l1 - mx);
      const float e2 = __expf(l2 - mx), e3 = __expf(l3 - mx);
      const float inv = 1.f / (e0 + e1 + e2 + e3);
      const float a0 = i0 ? e0 * inv : 0.f;
      const float a1 = i1 ? e1 * inv : 0.f;
      const float a2 = i2 ? e2 * inv : 0.f;
      const float a3 = i3 ? e3 * inv : 0.f;
      const int vb = 128 + poc0 * 2;
      const uint4* V0 = (const uint4*)(Pb + pn0 * 208 + vb);
      const uint4* V1 = (const uint4*)(Pb + pn1 * 208 + vb);
      const uint4* V2 = (const uint4*)(Pb + pn2 * 208 + vb);
      const uint4* V3 = (const uint4*)(Pb + pn3 * 208 + vb);
      #pragma unroll
      for (int half = 0; half < 2; ++half) {
        const uint4 w0 = V0[half], w1 = V1[half], w2 = V2[half], w3 = V3[half];
        const u32 u0[4] = {w0.x, w0.y, w0.z, w0.w};
        const u32 u1[4] = {w1.x, w1.y, w1.z, w1.w};
        const u32 u2[4] = {w2.x, w2.y, w2.z, w2.w};
        const u32 u3[4] = {w3.x, w3.y, w3.z, w3.w};
        #pragma unroll
        for (int p = 0; p < 4; ++p) {
          const int o = half * 8 + p * 2;
          float vlo = a0 * bf2f((u16)u0[p]) + a1 * bf2f((u16)u1[p])
                    + a2 * bf2f((u16)u2[p]) + a3 * bf2f((u16)u3[p]);
          float vhi = a0 * bf2f((u16)(u0[p] >> 16)) + a1 * bf2f((u16)(u1[p] >> 16))
                    + a2 * bf2f((u16)(u2[p] >> 16)) + a3 * bf2f((u16)(u3[p] >> 16));
          vlo = fmaxf(vlo, 0.f);
          vhi = fmaxf(vhi, 0.f);
          out[pgb + (size_t)o * HW]       = vlo + xres[o];
          out[pgb + (size_t)(o + 1) * HW] = vhi + xres[o + 1];
        }
      }
    }
    if (im < 7 && pact) {                          // prefetch next image residual
      const uint4* xr2 = (const uint4*)(xT + ((size_t)(bb + 1) * HW + ppx) * 256 + h * 32 + poc0);
      const uint4 r0 = xr2[0], r1 = xr2[1];
      const u32 uu[8] = {r0.x, r0.y, r0.z, r0.w, r1.x, r1.y, r1.z, r1.w};
      #pragma unroll
      for (int p = 0; p < 8; ++p) {
        xres[2 * p]     = bf2f((u16)uu[p]);
        xres[2 * p + 1] = bf2f((u16)(uu[p] >> 16));
      }
    }
    __syncthreads();
  }
}

// ---------------- workspace layout
constexpr size_t OFF_XT    = 0;
constexpr size_t SZ_XT     = (size_t)NPIX * 512 + 16384;
constexpr size_t OFF_WALL  = OFF_XT + SZ_XT;
constexpr size_t SZ_WALL   = (size_t)NTOT * 512;
constexpr size_t OFF_BALL  = OFF_WALL + SZ_WALL;
constexpr size_t OFF_M     = OFF_BALL + NTOT * 4;
constexpr size_t SZ_M      = 256 * 256 * 4;
constexpr size_t OFF_SX    = OFF_M + SZ_M;
constexpr size_t OFF_SALL  = OFF_SX + 256 * 4;
constexpr size_t OFF_TALL  = OFF_SALL + NTOT * 4;
constexpr size_t OFF_MPART = OFF_TALL + NTOT * 4;
constexpr size_t SZ_MPART  = (size_t)256 * 65536 * 4;   // 67 MB
constexpr size_t WS_NEEDED = OFF_MPART + SZ_MPART;

extern "C" void kernel_launch(void* const* d_in, const int* in_sizes, int n_in,
                              void* d_out, int out_size, void* d_ws, size_t ws_size,
                              hipStream_t stream) {
  (void)in_sizes; (void)n_in; (void)out_size;
  if (ws_size < WS_NEEDED) return;

  const float* x     = (const float*)d_in[0];
  const float* Wq    = (const float*)d_in[1];
  const float* bq    = (const float*)d_in[2];
  const float* Wk    = (const float*)d_in[3];
  const float* bk    = (const float*)d_in[4];
  const float* Wv    = (const float*)d_in[5];
  const float* bv    = (const float*)d_in[6];
  const float* gQ    = (const float*)d_in[7];
  const float* betaQ = (const float*)d_in[8];
  const float* gK    = (const float*)d_in[9];
  const float* betaK = (const float*)d_in[10];
  const float* gV    = (const float*)d_in[11];
  const float* betaV = (const float*)d_in[12];
  float* out = (float*)d_out;

  char* wsp = (char*)d_ws;
  u16*   xT    = (u16*)(wsp + OFF_XT);
  u16*   Wall  = (u16*)(wsp + OFF_WALL);
  float* ball  = (float*)(wsp + OFF_BALL);
  float* Mg    = (float*)(wsp + OFF_M);
  float* sx    = (float*)(wsp + OFF_SX);
  float* s_all = (float*)(wsp + OFF_SALL);
  float* t_all = (float*)(wsp + OFF_TALL);
  float* Mpart = (float*)(wsp + OFF_MPART);

  k_prep<<<NTOT, 256, 0, stream>>>(Wq, bq, Wk, bk, Wv, bv, Wall, ball, sx);
  k_M<<<256, 512, 0, stream>>>(x, xT, Mpart, sx);
  k_red<<<256, 256, 0, stream>>>(Mpart, Mg);
  k_stats2<<<NTOT, 256, 0, stream>>>(Mg, sx, Wq, bq, Wk, bk, Wv, bv,
                                     gQ, betaQ, gK, betaK, gV, betaV, s_all, t_all);
  k_fused<<<512, 768, 0, stream>>>(xT, Wall, ball, s_all, t_all, out);
}

// Round 25
// 346.904 us; speedup vs baseline: 1.5420x; 1.0246x over previous
//
#include <hip/hip_runtime.h>

typedef unsigned short u16;
typedef unsigned int   u32;

#define NB     512
#define NHEADS 8
#define HW     361
#define NPIX   184832      /* NB*HW */
#define NTOT   768
#define EPSBN  1e-5f
#define RS     0.17677669529663687f   /* sqrt(32)/32 */

typedef __bf16 bf16x8 __attribute__((ext_vector_type(8)));
typedef float  f32x4  __attribute__((ext_vector_type(4)));

__device__ __forceinline__ u16 f2bf(float f) {
  u32 u = __float_as_uint(f);
  u += 0x7fffu + ((u >> 16) & 1u);          // round-to-nearest-even
  return (u16)(u >> 16);
}
__device__ __forceinline__ float bf2f(u16 v) {
  return __uint_as_float(((u32)v) << 16);
}
__device__ __forceinline__ bf16x8 ldb8(const void* p) {
  return __builtin_bit_cast(bf16x8, *(const uint4*)p);
}
__device__ __forceinline__ float dot2(u32 a, u32 b) {
  return bf2f((u16)a) * bf2f((u16)b) + bf2f((u16)(a >> 16)) * bf2f((u16)(b >> 16));
}
__device__ __forceinline__ float dot8(uint4 a, uint4 b) {
  return dot2(a.x, b.x) + dot2(a.y, b.y) + dot2(a.z, b.z) + dot2(a.w, b.w);
}

// ---------------- kernel 0: W -> bf16 [768][256]; bias; zero sx
__global__ __launch_bounds__(256) void k_prep(
    const float* __restrict__ Wq, const float* __restrict__ bq,
    const float* __restrict__ Wk, const float* __restrict__ bk,
    const float* __restrict__ Wv, const float* __restrict__ bv,
    u16* __restrict__ Wall, float* __restrict__ ball,
    float* __restrict__ sx) {
  const int n = blockIdx.x, t = threadIdx.x;
  const float* src; const float* bs; int r;
  if (n < 256)      { src = Wq; bs = bq; r = n; }
  else if (n < 512) { src = Wk; bs = bk; r = n - 256; }
  else              { src = Wv; bs = bv; r = n - 512; }
  Wall[n * 256 + t] = f2bf(src[r * 256 + t]);
  if (t == 0) ball[n] = bs[r];
  if (n == 0) sx[t] = 0.f;
}

// ---------------- kernel 1: M partials + sx + fused xT write (x read ONCE)
// R16 version (known-good): 256 blocks (2 images) x 512 thr; acc[2][16]
__global__ __launch_bounds__(512) void k_M(
    const float* __restrict__ x, u16* __restrict__ xT,
    float* __restrict__ Mpart, float* __restrict__ sx) {
  __shared__ u16 Als[256 * 64];                    // 32 KB
  const int tid = threadIdx.x, g = blockIdx.x;     // images 2g, 2g+1
  const int lane = tid & 63, w = tid >> 6;         // 8 waves
  const int l15 = lane & 15, kq = lane >> 4;
  const int sc  = tid >> 4;                        // staging c low (0..31)
  const int sq  = tid & 15;                        // staging px quad
  const int wpx = tid & 63;                        // xT-write px in chunk
  const int wcs = tid >> 6;                        // xT-write c-slice (*32)
  char* Ab = (char*)Als;

  float sxp[8];
  f32x4 acc[2][16];
  #pragma unroll
  for (int i = 0; i < 8; ++i) sxp[i] = 0.f;
  #pragma unroll
  for (int f2 = 0; f2 < 16; ++f2) {
    acc[0][f2] = (f32x4){0.f, 0.f, 0.f, 0.f};
    acc[1][f2] = (f32x4){0.f, 0.f, 0.f, 0.f};
  }

  #pragma unroll 1
  for (int ch = 0; ch < 12; ++ch) {
    const int img = (ch >= 6) ? 1 : 0;
    const int px0 = (ch - img * 6) * 64;
    const int bb  = g * 2 + img;
    const int pb  = px0 + sq * 4;
    #pragma unroll
    for (int i = 0; i < 8; ++i) {
      const int c = sc + 32 * i;
      const float* xp = x + ((size_t)bb * 256 + c) * HW + pb;
      float v0, v1, v2, v3;
      if (pb + 3 < HW) {
        const float4 f4 = *(const float4*)xp;
        v0 = f4.x; v1 = f4.y; v2 = f4.z; v3 = f4.w;
      } else {
        v0 = (pb + 0 < HW) ? xp[0] : 0.f;
        v1 = (pb + 1 < HW) ? xp[1] : 0.f;
        v2 = (pb + 2 < HW) ? xp[2] : 0.f;
        v3 = (pb + 3 < HW) ? xp[3] : 0.f;
      }
      sxp[i] += v0 + v1 + v2 + v3;
      const u32 lo = (u32)f2bf(v0) | ((u32)f2bf(v1) << 16);
      const u32 hi = (u32)f2bf(v2) | ((u32)f2bf(v3) << 16);
      const int slot = (sq >> 1) ^ (c & 7);        // XOR swizzle
      *(uint2*)(Ab + c * 128 + slot * 16 + (sq & 1) * 8) = make_uint2(lo, hi);
    }
    __syncthreads();
    #pragma unroll
    for (int kk = 0; kk < 2; ++kk) {
      const int gl = kk * 4 + kq;
      const int so = ((gl ^ (l15 & 7)) << 4);
      const int r0 = w * 32 + l15;
      const bf16x8 a0 = ldb8(Ab + r0 * 128 + so);
      const bf16x8 a1 = ldb8(Ab + (r0 + 16) * 128 + so);
      #pragma unroll
      for (int f2 = 0; f2 < 16; ++f2) {
        const bf16x8 b = ldb8(Ab + (f2 * 16 + l15) * 128 + so);
        acc[0][f2] = __builtin_amdgcn_mfma_f32_16x16x32_bf16(a0, b, acc[0][f2], 0, 0, 0);
        acc[1][f2] = __builtin_amdgcn_mfma_f32_16x16x32_bf16(a1, b, acc[1][f2], 0, 0, 0);
      }
    }
    const int pxg = px0 + wpx;
    if (pxg < HW) {
      __align__(16) u16 tmp[32];
      #pragma unroll
      for (int j = 0; j < 32; ++j) {
        const int c = wcs * 32 + j;
        tmp[j] = Als[c * 64 + (((wpx >> 3) ^ (c & 7)) << 3) + (wpx & 7)];
      }
      uint4* dst = (uint4*)(xT + ((size_t)bb * HW + pxg) * 256 + wcs * 32);
      dst[0] = ((const uint4*)tmp)[0];
      dst[1] = ((const uint4*)tmp)[1];
      dst[2] = ((const uint4*)tmp)[2];
      dst[3] = ((const uint4*)tmp)[3];
    }
    __syncthreads();
  }
  float* mp = Mpart + (size_t)g * 65536;
  #pragma unroll
  for (int f1 = 0; f1 < 2; ++f1)
    #pragma unroll
    for (int f2 = 0; f2 < 16; ++f2)
      #pragma unroll
      for (int j = 0; j < 4; ++j) {
        const int c1 = w * 32 + f1 * 16 + kq * 4 + j;
        const int c2 = f2 * 16 + l15;
        mp[c1 * 256 + c2] = acc[f1][f2][j];
      }
  #pragma unroll
  for (int i = 0; i < 8; ++i) {
    float v = sxp[i];
    v += __shfl_down(v, 8); v += __shfl_down(v, 4);
    v += __shfl_down(v, 2); v += __shfl_down(v, 1);
    if (sq == 0) atomicAdd(&sx[sc + 32 * i], v);
  }
}

// ---------------- kernel 1c: reduce 256 partials -> Mg (deterministic)
__global__ __launch_bounds__(256) void k_red(const float* __restrict__ Mpart,
                                             float* __restrict__ Mg) {
  const int i = blockIdx.x * 256 + threadIdx.x;
  float s = 0.f;
  #pragma unroll 8
  for (int sl = 0; sl < 256; ++sl) s += Mpart[(size_t)sl * 65536 + i];
  Mg[i] = s;
}

// ---------------- kernel 2: finalize BN via moments: s_all, t_all
__global__ __launch_bounds__(256) void k_stats2(
    const float* __restrict__ Mg, const float* __restrict__ sx,
    const float* __restrict__ Wq, const float* __restrict__ bq,
    const float* __restrict__ Wk, const float* __restrict__ bk,
    const float* __restrict__ Wv, const float* __restrict__ bv,
    const float* __restrict__ gQ, const float* __restrict__ betaQ,
    const float* __restrict__ gK, const float* __restrict__ betaK,
    const float* __restrict__ gV, const float* __restrict__ betaV,
    float* __restrict__ s_all, float* __restrict__ t_all) {
  __shared__ float ws[256];
  __shared__ float r1[4], r2[4];
  const int n = blockIdx.x, i = threadIdx.x;
  const int which = n >> 8, r = n & 255;
  const float* src = (which == 0) ? Wq : (which == 1) ? Wk : Wv;
  const float wi = src[r * 256 + i];
  ws[i] = wi;
  __syncthreads();
  float colsum = 0.f;
  #pragma unroll 4
  for (int j = 0; j < 256; ++j) colsum += Mg[j * 256 + i] * ws[j];
  float p1 = wi * sx[i];
  float p2 = wi * colsum;
  p1 += __shfl_down(p1, 32); p2 += __shfl_down(p2, 32);
  p1 += __shfl_down(p1, 16); p2 += __shfl_down(p2, 16);
  p1 += __shfl_down(p1, 8);  p2 += __shfl_down(p2, 8);
  p1 += __shfl_down(p1, 4);  p2 += __shfl_down(p2, 4);
  p1 += __shfl_down(p1, 2);  p2 += __shfl_down(p2, 2);
  p1 += __shfl_down(p1, 1);  p2 += __shfl_down(p2, 1);
  const int wv = i >> 6;
  if ((i & 63) == 0) { r1[wv] = p1; r2[wv] = p2; }
  __syncthreads();
  if (i == 0) {
    const float S1 = r1[0] + r1[1] + r1[2] + r1[3];
    const float S2 = r2[0] + r2[1] + r2[2] + r2[3];
    const float* bs = (which == 0) ? bq : (which == 1) ? bk : bv;
    const float* gs = (which == 0) ? gQ : (which == 1) ? gK : gV;
    const float* be = (which == 0) ? betaQ : (which == 1) ? betaK : betaV;
    const float b = bs[r];
    const float P = (float)NPIX;
    const float mean = (S1 + P * b) / P;
    const float Ey2  = (S2 + 2.f * b * S1 + P * b * b) / P;
    const float var  = Ey2 - mean * mean;
    const float s    = gs[r] * rsqrtf(var + EPSBN);
    s_all[n] = s;
    t_all[n] = be[r] - s * mean;
  }
}

// ---------------- kernel 3: fused QKV-GEMM + neighbor attention
// 8 images/block; pair-cooperative softmax: threads (2k,2k+1) share px=k,
// split the 32-ch logit dots (even: ch0-15, odd: ch16-31), combine via shfl_xor
__global__ __launch_bounds__(768) void k_fused(
    const u16* __restrict__ xT, const u16* __restrict__ Wall,
    const float* __restrict__ ball,
    const float* __restrict__ s_all, const float* __restrict__ t_all,
    float* __restrict__ out) {
  __shared__ u16   Wl[96 * 256];                   // 48 KB, XOR-swizzled rows
  __shared__ __align__(16) u16 P[HW * 104];        // 75,088 B: [px][Q|K|V]
  __shared__ float stl[2 * 96];
  const int tid = threadIdx.x;
  const int wg  = blockIdx.x;                      // 0..511
  const int xcd = wg & 7, ii = wg >> 3;            // ii 0..63
  const int h   = ii & 7;
  const int oc8 = xcd * 8 + (ii >> 3);             // image octet 0..63
  const int bb0 = oc8 * 8;
  const char* Pb = (const char*)P;

  const int lane = tid & 63, wv = tid >> 6;
  const int l15 = lane & 15, kq = lane >> 4;

  const bool pact  = tid < 2 * HW;
  const int  ppx   = tid >> 1;                     // pair-shared pixel
  const int  poc0  = (tid & 1) * 16;               // oc half
  const int  chalf = (tid & 1) * 32;               // Q/K channel-half byte offset

  uint4 bfr[16];
  {
    const u16* xTb = xT + (size_t)bb0 * HW * 256;
    #pragma unroll
    for (int ks = 0; ks < 8; ++ks) {
      bfr[2 * ks]     = *(const uint4*)(xTb + (size_t)(wv * 32      + l15) * 256 + ks * 32 + kq * 8);
      bfr[2 * ks + 1] = *(const uint4*)(xTb + (size_t)(wv * 32 + 16 + l15) * 256 + ks * 32 + kq * 8);
    }
  }
  // residual prefetch from bf16 xT (channels h*32+poc0 .. +16, contiguous)
  float xres[16];
  if (pact) {
    const uint4* xr = (const uint4*)(xT + ((size_t)bb0 * HW + ppx) * 256 + h * 32 + poc0);
    const uint4 r0 = xr[0], r1 = xr[1];
    const u32 uu[8] = {r0.x, r0.y, r0.z, r0.w, r1.x, r1.y, r1.z, r1.w};
    #pragma unroll
    for (int p = 0; p < 8; ++p) {
      xres[2 * p]     = bf2f((u16)uu[p]);
      xres[2 * p + 1] = bf2f((u16)(uu[p] >> 16));
    }
  }
  if (tid < 96) {
    const int which = tid >> 5, c32 = tid & 31;
    const int n = which * 256 + h * 32 + c32;
    float s = s_all[n];
    float t = s * ball[n] + t_all[n];
    if (tid < 32) { s *= RS; t *= RS; }
    stl[tid] = s; stl[96 + tid] = t;
  }
  #pragma unroll
  for (int i = 0; i < 4; ++i) {
    const int gi = tid + i * 768;
    const int lr = gi >> 5, gg = gi & 31;
    const int which = lr >> 5, c32 = lr & 31;
    uint4 v = *(const uint4*)(Wall + (size_t)(which * 256 + h * 32 + c32) * 256 + gg * 8);
    const int slot = gg ^ (lr & 7);
    *(uint4*)((char*)Wl + lr * 512 + slot * 16) = v;
  }
  __syncthreads();

  #pragma unroll 1
  for (int im = 0; im < 8; ++im) {
    const int bb = bb0 + im;
    f32x4 acc[6][2];
    #pragma unroll
    for (int f = 0; f < 6; ++f) {
      acc[f][0] = (f32x4){0.f, 0.f, 0.f, 0.f};
      acc[f][1] = (f32x4){0.f, 0.f, 0.f, 0.f};
    }
    #pragma unroll
    for (int ks = 0; ks < 8; ++ks) {
      bf16x8 b0 = __builtin_bit_cast(bf16x8, bfr[2 * ks]);
      bf16x8 b1 = __builtin_bit_cast(bf16x8, bfr[2 * ks + 1]);
      const int slot = ((ks * 4 + kq) ^ (l15 & 7)) * 16;
      #pragma unroll
      for (int f = 0; f < 6; ++f) {
        const int lr = (f >> 1) * 32 + (f & 1) * 16 + l15;
        bf16x8 a = ldb8((const char*)Wl + lr * 512 + slot);
        acc[f][0] = __builtin_amdgcn_mfma_f32_16x16x32_bf16(a, b0, acc[f][0], 0, 0, 0);
        acc[f][1] = __builtin_amdgcn_mfma_f32_16x16x32_bf16(a, b1, acc[f][1], 0, 0, 0);
      }
    }
    if (im < 7) {                                  // prefetch next image B-frags
      const u16* xTb2 = xT + (size_t)(bb + 1) * HW * 256;
      #pragma unroll
      for (int ks = 0; ks < 8; ++ks) {
        bfr[2 * ks]     = *(const uint4*)(xTb2 + (size_t)(wv * 32      + l15) * 256 + ks * 32 + kq * 8);
        bfr[2 * ks + 1] = *(const uint4*)(xTb2 + (size_t)(wv * 32 + 16 + l15) * 256 + ks * 32 + kq * 8);
      }
    }
    #pragma unroll
    for (int f = 0; f < 6; ++f) {
      const int ch0 = f * 16 + kq * 4;
      const float s0 = stl[ch0],     t0 = stl[96 + ch0];
      const float s1 = stl[ch0 + 1], t1 = stl[96 + ch0 + 1];
      const float s2 = stl[ch0 + 2], t2 = stl[96 + ch0 + 2];
      const float s3 = stl[ch0 + 3], t3 = stl[96 + ch0 + 3];
      #pragma unroll
      for (int p2 = 0; p2 < 2; ++p2) {
        const int px = wv * 32 + p2 * 16 + l15;
        if (px < HW) {
          const u32 lo = (u32)f2bf(s0 * acc[f][p2][0] + t0)
                       | ((u32)f2bf(s1 * acc[f][p2][1] + t1) << 16);
          const u32 hi = (u32)f2bf(s2 * acc[f][p2][2] + t2)
                       | ((u32)f2bf(s3 * acc[f][p2][3] + t3) << 16);
          *(uint2*)((char*)P + px * 208 + f * 32 + kq * 8) = make_uint2(lo, hi);
        }
      }
    }
    __syncthreads();

    // fused pair-cooperative softmax + weighted-V + ReLU + residual
    if (pact) {
      const int px = ppx;
      const size_t pgb = ((size_t)bb * 256 + h * 32 + poc0) * HW + px;
      const int yy = px / 19, xx = px - yy * 19;
      const bool i0 = yy > 0, i1 = yy < 18, i2 = xx > 0, i3 = xx < 18;
      const int pn0 = i0 ? px - 19 : px, pn1 = i1 ? px + 19 : px;
      const int pn2 = i2 ? px - 1  : px, pn3 = i3 ? px + 1  : px;
      // half-channel logit partials (even lane: ch0-15, odd: ch16-31)
      const uint4* Qp = (const uint4*)(Pb + px * 208 + chalf);
      const uint4 q0 = Qp[0], q1 = Qp[1];
      const uint4* K0 = (const uint4*)(Pb + pn0 * 208 + 64 + chalf);
      const uint4* K1 = (const uint4*)(Pb + pn1 * 208 + 64 + chalf);
      const uint4* K2 = (const uint4*)(Pb + pn2 * 208 + 64 + chalf);
      const uint4* K3 = (const uint4*)(Pb + pn3 * 208 + 64 + chalf);
      float p0 = dot8(q0, K0[0]) + dot8(q1, K0[1]);
      float p1 = dot8(q0, K1[0]) + dot8(q1, K1[1]);
      float p2 = dot8(q0, K2[0]) + dot8(q1, K2[1]);
      float p3 = dot8(q0, K3[0]) + dot8(q1, K3[1]);
      float l0 = p0 + __shfl_xor(p0, 1);
      float l1 = p1 + __shfl_xor(p1, 1);
      float l2 = p2 + __shfl_xor(p2, 1);
      float l3 = p3 + __shfl_xor(p3, 1);
      l0 = i0 ? l0 : 0.f; l1 = i1 ? l1 : 0.f;
      l2 = i2 ? l2 : 0.f; l3 = i3 ? l3 : 0.f;
      const float mx = fmaxf(fmaxf(l0, l1), fmaxf(l2, l3));
      const float e0 = __expf(l0 - mx), e1 = __expf(l1 - mx);
      const float e2 = __expf(l2 - mx), e3 = __expf(l3 - mx);
      const float inv = 1.f / (e0 + e1 + e2 + e3);
      const float a0 = i0 ? e0 * inv : 0.f;
      const float a1 = i1 ? e1 * inv : 0.f;
      const float a2 = i2 ? e2 * inv : 0.f;
      const float a3 = i3 ? e3 * inv : 0.f;
      const int vb = 128 + poc0 * 2;
      const uint4* V0 = (const uint4*)(Pb + pn0 * 208 + vb);
      const uint4* V1 = (const uint4*)(Pb + pn1 * 208 + vb);
      const uint4* V2 = (const uint4*)(Pb + pn2 * 208 + vb);
      const uint4* V3 = (const uint4*)(Pb + pn3 * 208 + vb);
      #pragma unroll
      for (int half = 0; half < 2; ++half) {
        const uint4 w0 = V0[half], w1 = V1[half], w2 = V2[half], w3 = V3[half];
        const u32 u0[4] = {w0.x, w0.y, w0.z, w0.w};
        const u32 u1[4] = {w1.x, w1.y, w1.z, w1.w};
        const u32 u2[4] = {w2.x, w2.y, w2.z, w2.w};
        const u32 u3[4] = {w3.x, w3.y, w3.z, w3.w};
        #pragma unroll
        for (int p = 0; p < 4; ++p) {
          const int o = half * 8 + p * 2;
          float vlo = a0 * bf2f((u16)u0[p]) + a1 * bf2f((u16)u1[p])
                    + a2 * bf2f((u16)u2[p]) + a3 * bf2f((u16)u3[p]);
          float vhi = a0 * bf2f((u16)(u0[p] >> 16)) + a1 * bf2f((u16)(u1[p] >> 16))
                    + a2 * bf2f((u16)(u2[p] >> 16)) + a3 * bf2f((u16)(u3[p] >> 16));
          vlo = fmaxf(vlo, 0.f);
          vhi = fmaxf(vhi, 0.f);
          out[pgb + (size_t)o * HW]       = vlo + xres[o];
          out[pgb + (size_t)(o + 1) * HW] = vhi + xres[o + 1];
        }
      }
    }
    if (im < 7 && pact) {                          // prefetch next image residual
      const uint4* xr2 = (const uint4*)(xT + ((size_t)(bb + 1) * HW + ppx) * 256 + h * 32 + poc0);
      const uint4 r0 = xr2[0], r1 = xr2[1];
      const u32 uu[8] = {r0.x, r0.y, r0.z, r0.w, r1.x, r1.y, r1.z, r1.w};
      #pragma unroll
      for (int p = 0; p < 8; ++p) {
        xres[2 * p]     = bf2f((u16)uu[p]);
        xres[2 * p + 1] = bf2f((u16)(uu[p] >> 16));
      }
    }
    __syncthreads();
  }
}

// ---------------- workspace layout
constexpr size_t OFF_XT    = 0;
constexpr size_t SZ_XT     = (size_t)NPIX * 512 + 16384;
constexpr size_t OFF_WALL  = OFF_XT + SZ_XT;
constexpr size_t SZ_WALL   = (size_t)NTOT * 512;
constexpr size_t OFF_BALL  = OFF_WALL + SZ_WALL;
constexpr size_t OFF_M     = OFF_BALL + NTOT * 4;
constexpr size_t SZ_M      = 256 * 256 * 4;
constexpr size_t OFF_SX    = OFF_M + SZ_M;
constexpr size_t OFF_SALL  = OFF_SX + 256 * 4;
constexpr size_t OFF_TALL  = OFF_SALL + NTOT * 4;
constexpr size_t OFF_MPART = OFF_TALL + NTOT * 4;
constexpr size_t SZ_MPART  = (size_t)256 * 65536 * 4;   // 67 MB
constexpr size_t WS_NEEDED = OFF_MPART + SZ_MPART;

extern "C" void kernel_launch(void* const* d_in, const int* in_sizes, int n_in,
                              void* d_out, int out_size, void* d_ws, size_t ws_size,
                              hipStream_t stream) {
  (void)in_sizes; (void)n_in; (void)out_size;
  if (ws_size < WS_NEEDED) return;

  const float* x     = (const float*)d_in[0];
  const float* Wq    = (const float*)d_in[1];
  const float* bq    = (const float*)d_in[2];
  const float* Wk    = (const float*)d_in[3];
  const float* bk    = (const float*)d_in[4];
  const float* Wv    = (const float*)d_in[5];
  const float* bv    = (const float*)d_in[6];
  const float* gQ    = (const float*)d_in[7];
  const float* betaQ = (const float*)d_in[8];
  const float* gK    = (const float*)d_in[9];
  const float* betaK = (const float*)d_in[10];
  const float* gV    = (const float*)d_in[11];
  const float* betaV = (const float*)d_in[12];
  float* out = (float*)d_out;

  char* wsp = (char*)d_ws;
  u16*   xT    = (u16*)(wsp + OFF_XT);
  u16*   Wall  = (u16*)(wsp + OFF_WALL);
  float* ball  = (float*)(wsp + OFF_BALL);
  float* Mg    = (float*)(wsp + OFF_M);
  float* sx    = (float*)(wsp + OFF_SX);
  float* s_all = (float*)(wsp + OFF_SALL);
  float* t_all = (float*)(wsp + OFF_TALL);
  float* Mpart = (float*)(wsp + OFF_MPART);

  k_prep<<<NTOT, 256, 0, stream>>>(Wq, bq, Wk, bk, Wv, bv, Wall, ball, sx);
  k_M<<<256, 512, 0, stream>>>(x, xT, Mpart, sx);
  k_red<<<256, 256, 0, stream>>>(Mpart, Mg);
  k_stats2<<<NTOT, 256, 0, stream>>>(Mg, sx, Wq, bq, Wk, bk, Wv, bv,
                                     gQ, betaQ, gK, betaK, gV, betaV, s_all, t_all);
  k_fused<<<512, 768, 0, stream>>>(xT, Wall, ball, s_all, t_all, out);
}